// Round 1
// baseline (470.224 us; speedup 1.0000x reference)
//
#include <hip/hip_runtime.h>

#define HIDDEN 50
#define IN_DIM 12
#define NZ 4

// tanh(x) = 1 - 2/(1+e^{2x}) ; e^{2x} = 2^{x * 2*log2(e)}
__device__ __forceinline__ float fast_tanh(float x) {
    float e = __builtin_amdgcn_exp2f(x * 2.8853900817779268f);
    return 1.0f - 2.0f * __builtin_amdgcn_rcpf(e + 1.0f);
}

__global__ __launch_bounds__(256, 2) void mlp_fused(
    const float* __restrict__ X,
    const float* __restrict__ U_W, const float* __restrict__ U_b,
    const float* __restrict__ V_W, const float* __restrict__ V_b,
    const float* __restrict__ H_Wm, const float* __restrict__ H_b,
    const float* __restrict__ Z_W, const float* __restrict__ Z_b,
    const float* __restrict__ F_W, const float* __restrict__ F_b,
    float* __restrict__ out, int N)
{
    int i = blockIdx.x * 256 + threadIdx.x;
    if (i >= N) return;

    float t  = X[2 * i];
    float xs = X[2 * i + 1];

    // Fourier embedding: [t, 1, cos(m*w*xs) m=1..5, sin(m*w*xs) m=1..5], w = pi/2
    float xe[IN_DIM];
    xe[0] = t;
    xe[1] = 1.0f;
    float s1, c1;
    __sincosf(1.5707963267948966f * xs, &s1, &c1);
    xe[2] = c1;
    xe[7] = s1;
    float cm = c1, sm = s1;
    #pragma unroll
    for (int m = 2; m <= 5; ++m) {
        float cn = cm * c1 - sm * s1;
        float sn = sm * c1 + cm * s1;
        xe[1 + m] = cn;
        xe[6 + m] = sn;
        cm = cn; sm = sn;
    }

    // U, D (=V-U), H in registers
    float U[HIDDEN], D[HIDDEN], Hh[HIDDEN];
    #pragma unroll
    for (int j = 0; j < HIDDEN; ++j) {
        U[j]  = U_b[j];
        D[j]  = V_b[j];
        Hh[j] = H_b[j];
    }
    #pragma unroll
    for (int k = 0; k < IN_DIM; ++k) {
        float x = xe[k];
        #pragma unroll
        for (int j = 0; j < HIDDEN; ++j) {
            U[j]  = fmaf(x, U_W[k * HIDDEN + j], U[j]);
            D[j]  = fmaf(x, V_W[k * HIDDEN + j], D[j]);
            Hh[j] = fmaf(x, H_Wm[k * HIDDEN + j], Hh[j]);
        }
    }
    #pragma unroll
    for (int j = 0; j < HIDDEN; ++j) {
        float u = fast_tanh(U[j]);
        float v = fast_tanh(D[j]);
        Hh[j]   = fast_tanh(Hh[j]);
        U[j] = u;
        D[j] = v - u;
    }

    // 4 gated Z layers; keep layer loop rolled so the 2500-FMA body fits I$
    #pragma unroll 1
    for (int l = 0; l < NZ; ++l) {
        const float* W = Z_W + l * (HIDDEN * HIDDEN);
        const float* b = Z_b + l * HIDDEN;
        float Zt[HIDDEN];
        #pragma unroll
        for (int j = 0; j < HIDDEN; ++j) Zt[j] = b[j];
        #pragma unroll
        for (int k = 0; k < HIDDEN; ++k) {
            float h = Hh[k];
            #pragma unroll
            for (int j = 0; j < HIDDEN; ++j)
                Zt[j] = fmaf(h, W[k * HIDDEN + j], Zt[j]);
        }
        #pragma unroll
        for (int j = 0; j < HIDDEN; ++j) {
            float z = fast_tanh(Zt[j]);
            Hh[j] = fmaf(z, D[j], U[j]);   // (1-z)*U + z*V = U + z*(V-U)
        }
    }

    float acc = F_b[0];
    #pragma unroll
    for (int j = 0; j < HIDDEN; ++j)
        acc = fmaf(Hh[j], F_W[j], acc);
    out[i] = acc;
}

extern "C" void kernel_launch(void* const* d_in, const int* in_sizes, int n_in,
                              void* d_out, int out_size, void* d_ws, size_t ws_size,
                              hipStream_t stream) {
    const float* X   = (const float*)d_in[0];
    const float* U_W = (const float*)d_in[1];
    const float* U_b = (const float*)d_in[2];
    const float* V_W = (const float*)d_in[3];
    const float* V_b = (const float*)d_in[4];
    const float* H_W = (const float*)d_in[5];
    const float* H_b = (const float*)d_in[6];
    const float* Z_W = (const float*)d_in[7];
    const float* Z_b = (const float*)d_in[8];
    const float* F_W = (const float*)d_in[9];
    const float* F_b = (const float*)d_in[10];
    float* out = (float*)d_out;

    int N = in_sizes[0] / 2;
    int blocks = (N + 255) / 256;
    hipLaunchKernelGGL(mlp_fused, dim3(blocks), dim3(256), 0, stream,
                       X, U_W, U_b, V_W, V_b, H_W, H_b, Z_W, Z_b, F_W, F_b,
                       out, N);
}

// Round 2
// 145.202 us; speedup vs baseline: 3.2384x; 3.2384x over previous
//
#include <hip/hip_runtime.h>

typedef _Float16 half8 __attribute__((ext_vector_type(8)));
typedef float f32x4 __attribute__((ext_vector_type(4)));

#define HID 50

__device__ __forceinline__ float fast_tanh(float x) {
    float e = __builtin_amdgcn_exp2f(x * 2.8853900817779268f);
    return 1.0f - 2.0f * __builtin_amdgcn_rcpf(e + 1.0f);
}

// LDS f16 tile [16 rows][64 cols], XOR-swizzled in 16B slots: idx(row,c)
__device__ __forceinline__ int swz_idx(int row, int c) {
    return row * 64 + ((((c >> 3) ^ (row & 7)) << 3) | (c & 7));
}

// ---------- weight prep: 44 blocks x 64 threads ----------
// ws layout (half8 units): blocks of 64 half8 (1KB each), fragment-linear:
//   b in [0,12):  UVH  b = m*4 + nt          (K=32 padded from 12, bias folded at k==1)
//   b in [12,44): Z    b = 12 + ((li*4+nt)*2 + ks)   (K=64 padded from 50, bias row at k==50)
// entry: lane l, elem v  ->  B[k = ks*32 + 8*(l>>4)+v][col = (l&15)+16*nt]
__global__ void prep_weights(const float* __restrict__ U_W, const float* __restrict__ U_b,
                             const float* __restrict__ V_W, const float* __restrict__ V_b,
                             const float* __restrict__ H_W, const float* __restrict__ H_b,
                             const float* __restrict__ Z_W, const float* __restrict__ Z_b,
                             _Float16* __restrict__ ws) {
    int b = blockIdx.x;
    int l = threadIdx.x;
    int g = l >> 4, cl = l & 15;
    half8 h;
    if (b < 12) {
        int m = b >> 2, nt = b & 3;
        const float* W = (m == 0) ? U_W : (m == 1) ? V_W : H_W;
        const float* B = (m == 0) ? U_b : (m == 1) ? V_b : H_b;
        int c = cl + 16 * nt;
        #pragma unroll
        for (int v = 0; v < 8; ++v) {
            int k = 8 * g + v;
            float x = 0.f;
            if (k < 12 && c < HID) { x = W[k * HID + c]; if (k == 1) x += B[c]; }
            h[v] = (_Float16)x;
        }
    } else {
        int zb = b - 12;
        int li = zb >> 3, nt = (zb >> 1) & 3, ks = zb & 1;
        int c = cl + 16 * nt;
        #pragma unroll
        for (int v = 0; v < 8; ++v) {
            int k = ks * 32 + 8 * g + v;
            float x = 0.f;
            if (c < HID) {
                if (k < HID)       x = Z_W[li * (HID * HID) + k * HID + c];
                else if (k == HID) x = Z_b[li * HID + c];   // bias row (A col 50 == 1.0)
            }
            h[v] = (_Float16)x;
        }
    }
    *(half8*)(ws + (size_t)b * 512 + (size_t)l * 8) = h;
}

// ---------- main: 1 block = 4 waves, 1 wave = 32 points (2 M-subtiles of 16) ----------
__global__ __launch_bounds__(256, 2) void mlp_mfma(
        const float* __restrict__ X, const _Float16* __restrict__ ws,
        const float* __restrict__ F_W, const float* __restrict__ F_b,
        float* __restrict__ out) {
    // wave-private tiles: no barriers anywhere (per-wave in-order DS)
    __shared__ _Float16 lds[4][2][1024];   // [wave][subtile][16x64 swizzled]  = 16 KB
    const int tid = threadIdx.x;
    const int wave = tid >> 6, l = tid & 63;
    const int g = l >> 4, cl = l & 15;
    const int pbase = blockIdx.x * 128 + wave * 32;
    const half8* wsv = (const half8*)ws;

    // ---- Fourier embedding A-fragments (each lane computes exactly its 8 k-values) ----
    half8 axe[2];
    #pragma unroll
    for (int st = 0; st < 2; ++st) {
        int p = pbase + st * 16 + cl;
        float2 xv = *(const float2*)(X + 2 * p);
        float t = xv.x, xs = xv.y;
        float s1, c1;
        __sincosf(1.5707963267948966f * xs, &s1, &c1);
        float cc[5], ss[5];
        cc[0] = c1; ss[0] = s1;
        #pragma unroll
        for (int m = 1; m < 5; ++m) {
            cc[m] = cc[m - 1] * c1 - ss[m - 1] * s1;
            ss[m] = ss[m - 1] * c1 + cc[m - 1] * s1;
        }
        float e0[8] = {t, 1.f, cc[0], cc[1], cc[2], cc[3], cc[4], ss[0]};
        float e1[8] = {ss[1], ss[2], ss[3], ss[4], 0.f, 0.f, 0.f, 0.f};
        half8 a;
        #pragma unroll
        for (int v = 0; v < 8; ++v) {
            float x = (g == 0) ? e0[v] : (g == 1) ? e1[v] : 0.f;
            a[v] = (_Float16)x;
        }
        axe[st] = a;
    }

    // ---- U, V, H GEMMs (K=32, one MFMA per (matmul, subtile, ntile)) ----
    f32x4 accU[2][4], accV[2][4], accH[2][4];
    #pragma unroll
    for (int nt = 0; nt < 4; ++nt) {
        half8 bU = wsv[(0 * 4 + nt) * 64 + l];
        half8 bV = wsv[(1 * 4 + nt) * 64 + l];
        half8 bH = wsv[(2 * 4 + nt) * 64 + l];
        #pragma unroll
        for (int st = 0; st < 2; ++st) {
            f32x4 z = {0.f, 0.f, 0.f, 0.f};
            accU[st][nt] = __builtin_amdgcn_mfma_f32_16x16x32_f16(axe[st], bU, z, 0, 0, 0);
            accV[st][nt] = __builtin_amdgcn_mfma_f32_16x16x32_f16(axe[st], bV, z, 0, 0, 0);
            accH[st][nt] = __builtin_amdgcn_mfma_f32_16x16x32_f16(axe[st], bH, z, 0, 0, 0);
        }
    }

    // U, D=V-U stay in registers (D-fragment layout matches all later layers);
    // H goes to the LDS tile as next layer's A operand. col 50 := 1.0 (bias lane).
    f32x4 Ug[2][4], Dg[2][4];
    #pragma unroll
    for (int st = 0; st < 2; ++st)
    #pragma unroll
    for (int nt = 0; nt < 4; ++nt) {
        int c = cl + 16 * nt;
        #pragma unroll
        for (int r4 = 0; r4 < 4; ++r4) {
            float u = fast_tanh(accU[st][nt][r4]);
            float v = fast_tanh(accV[st][nt][r4]);
            float h = fast_tanh(accH[st][nt][r4]);
            Ug[st][nt][r4] = u;
            Dg[st][nt][r4] = v - u;
            int row = 4 * g + r4;
            if (c == HID) h = 1.0f;
            lds[wave][st][swz_idx(row, c)] = (_Float16)h;
        }
    }

    // ---- 4 gated Z layers: read A-frags, 2-step-K MFMA, tanh+gate, write back ----
    #pragma unroll 1
    for (int li = 0; li < 4; ++li) {
        half8 bz[4][2];
        #pragma unroll
        for (int nt = 0; nt < 4; ++nt)
            #pragma unroll
            for (int ks = 0; ks < 2; ++ks)
                bz[nt][ks] = wsv[768 + ((li * 4 + nt) * 2 + ks) * 64 + l];
        #pragma unroll
        for (int st = 0; st < 2; ++st) {
            const half8* tp = (const half8*)&lds[wave][st][0];
            half8 a0 = tp[cl * 8 + ((0 + g) ^ (cl & 7))];
            half8 a1 = tp[cl * 8 + ((4 + g) ^ (cl & 7))];
            #pragma unroll
            for (int nt = 0; nt < 4; ++nt) {
                f32x4 z4 = {0.f, 0.f, 0.f, 0.f};
                f32x4 acc = __builtin_amdgcn_mfma_f32_16x16x32_f16(a0, bz[nt][0], z4, 0, 0, 0);
                acc = __builtin_amdgcn_mfma_f32_16x16x32_f16(a1, bz[nt][1], acc, 0, 0, 0);
                int c = cl + 16 * nt;
                #pragma unroll
                for (int r4 = 0; r4 < 4; ++r4) {
                    float z = fast_tanh(acc[r4]);
                    float h = fmaf(z, Dg[st][nt][r4], Ug[st][nt][r4]);
                    int row = 4 * g + r4;
                    if (c == HID) h = 1.0f;
                    lds[wave][st][swz_idx(row, c)] = (_Float16)h;
                }
            }
        }
    }

    // ---- epilogue: out = H @ F_W + F_b, read final tile back in A-frag pattern ----
    float part[2];
    #pragma unroll
    for (int st = 0; st < 2; ++st) {
        const half8* tp = (const half8*)&lds[wave][st][0];
        half8 h0 = tp[cl * 8 + ((0 + g) ^ (cl & 7))];
        half8 h1 = tp[cl * 8 + ((4 + g) ^ (cl & 7))];
        float s = 0.f;
        #pragma unroll
        for (int v = 0; v < 8; ++v) {
            int c0 = 8 * g + v;
            int c1i = 32 + 8 * g + v;
            float w0 = (c0 < HID) ? F_W[c0] : 0.f;
            float w1 = (c1i < HID) ? F_W[c1i] : 0.f;
            s += (float)h0[v] * w0 + (float)h1[v] * w1;
        }
        part[st] = s;
    }
    part[0] += __shfl_xor(part[0], 16);
    part[0] += __shfl_xor(part[0], 32);
    part[1] += __shfl_xor(part[1], 16);
    part[1] += __shfl_xor(part[1], 32);
    if (l < 16) {
        float fb = F_b[0];
        out[pbase + cl]      = part[0] + fb;
        out[pbase + 16 + cl] = part[1] + fb;
    }
}

extern "C" void kernel_launch(void* const* d_in, const int* in_sizes, int n_in,
                              void* d_out, int out_size, void* d_ws, size_t ws_size,
                              hipStream_t stream) {
    const float* X   = (const float*)d_in[0];
    const float* U_W = (const float*)d_in[1];
    const float* U_b = (const float*)d_in[2];
    const float* V_W = (const float*)d_in[3];
    const float* V_b = (const float*)d_in[4];
    const float* H_W = (const float*)d_in[5];
    const float* H_b = (const float*)d_in[6];
    const float* Z_W = (const float*)d_in[7];
    const float* Z_b = (const float*)d_in[8];
    const float* F_W = (const float*)d_in[9];
    const float* F_b = (const float*)d_in[10];
    float* out = (float*)d_out;
    _Float16* ws16 = (_Float16*)d_ws;

    int N = in_sizes[0] / 2;          // 1048576; 128 points per block
    prep_weights<<<44, 64, 0, stream>>>(U_W, U_b, V_W, V_b, H_W, H_b, Z_W, Z_b, ws16);
    int blocks = N / 128;
    mlp_mfma<<<blocks, 256, 0, stream>>>(X, ws16, F_W, F_b, out);
}

// Round 3
// 122.627 us; speedup vs baseline: 3.8346x; 1.1841x over previous
//
#include <hip/hip_runtime.h>

typedef _Float16 half8 __attribute__((ext_vector_type(8)));
typedef _Float16 half2v __attribute__((ext_vector_type(2)));
typedef float f32x4 __attribute__((ext_vector_type(4)));
typedef unsigned int uint2v __attribute__((ext_vector_type(2)));
typedef unsigned int uint4v __attribute__((ext_vector_type(4)));

#define HID 50

__device__ __forceinline__ float fast_tanh(float x) {
    float e = __builtin_amdgcn_exp2f(x * 2.8853900817779268f);
    return 1.0f - 2.0f * __builtin_amdgcn_rcpf(e + 1.0f);
}
__device__ __forceinline__ unsigned int pk2(float a, float b) {
    auto h = __builtin_amdgcn_cvt_pkrtz(a, b);
    return __builtin_bit_cast(unsigned int, h);
}
__device__ __forceinline__ half2v upk(unsigned int w) {
    return __builtin_bit_cast(half2v, w);
}

// ---------- weight prep: 45 blocks x 64 threads ----------
// half8-block b, lane l (g=l>>4, cl=l&15), elem v -> W[k = 8g+v (+32ks)][col = cl+16nt]
//   b in [0,12):  UVH  b = m*4 + nt           (K=32 padded from 12, bias folded at k==1)
//   b in [12,44): Z    b = 12 + (li*4+nt)*2 + ks  (K=64 padded from 50, bias row at k==50)
//   block 44: F_W padded to 64 floats at f16-offset 22528
__global__ void prep_weights(const float* __restrict__ U_W, const float* __restrict__ U_b,
                             const float* __restrict__ V_W, const float* __restrict__ V_b,
                             const float* __restrict__ H_W, const float* __restrict__ H_b,
                             const float* __restrict__ Z_W, const float* __restrict__ Z_b,
                             const float* __restrict__ F_W,
                             _Float16* __restrict__ ws) {
    int b = blockIdx.x;
    int l = threadIdx.x;
    if (b == 44) {
        float* Fp = (float*)(ws + 22528);
        Fp[l] = (l < HID) ? F_W[l] : 0.f;
        return;
    }
    int g = l >> 4, cl = l & 15;
    half8 h;
    if (b < 12) {
        int m = b >> 2, nt = b & 3;
        const float* W = (m == 0) ? U_W : (m == 1) ? V_W : H_W;
        const float* B = (m == 0) ? U_b : (m == 1) ? V_b : H_b;
        int c = cl + 16 * nt;
        #pragma unroll
        for (int v = 0; v < 8; ++v) {
            int k = 8 * g + v;
            float x = 0.f;
            if (k < 12 && c < HID) { x = W[k * HID + c]; if (k == 1) x += B[c]; }
            h[v] = (_Float16)x;
        }
    } else {
        int zb = b - 12;
        int li = zb >> 3, nt = (zb >> 1) & 3, ks = zb & 1;
        int c = cl + 16 * nt;
        #pragma unroll
        for (int v = 0; v < 8; ++v) {
            int k = ks * 32 + 8 * g + v;
            float x = 0.f;
            if (c < HID) {
                if (k < HID)       x = Z_W[li * (HID * HID) + k * HID + c];
                else if (k == HID) x = Z_b[li * HID + c];   // bias row (input feature 50 == 1.0)
            }
            h[v] = (_Float16)x;
        }
    }
    *(half8*)(ws + (size_t)b * 512 + (size_t)l * 8) = h;
}

// ---------- main: 1 block = 4 waves, 1 wave = 32 points (2 subtiles of 16) ----------
// Transposed GEMMs: D = Wfrag(A) x Xfrag(B); D[feature=4g+r (+16ns)][point=cl].
// Inter-layer tile: per (wave,st) 16 cols (points) x 32 words (feature pairs),
// word p at column cl stored at word idx  cl*32 + (p ^ ((cl&7)<<2)).
__global__ __launch_bounds__(256, 3) void mlp_mfma(
        const float* __restrict__ X, const _Float16* __restrict__ ws,
        const float* __restrict__ F_b, float* __restrict__ out) {
    __shared__ __align__(16) unsigned int tile[4][2][512];   // 16 KB
    const int tid = threadIdx.x;
    const int wave = tid >> 6, l = tid & 63;
    const int g = l >> 4, cl = l & 15;
    const int pbase = blockIdx.x * 128 + wave * 32;
    const half8* __restrict__ wsv = (const half8*)ws;
    const float* __restrict__ Fp = (const float*)(ws + 22528);

    const int S = (cl & 7) << 2;
    int ow[4], orx[2];
    #pragma unroll
    for (int ns = 0; ns < 4; ++ns) ow[ns] = ((8 * ns + 2 * g) ^ S) + cl * 32;
    orx[0] = ((4 * g) ^ S) + cl * 32;
    orx[1] = ((16 + 4 * g) ^ S) + cl * 32;

    // ---- Fourier embedding B-frags: lane holds Xe[point=cl][k=8g+v] ----
    half8 axe[2];
    #pragma unroll
    for (int st = 0; st < 2; ++st) {
        int p = pbase + st * 16 + cl;
        float2 xv = *(const float2*)(X + 2 * p);
        float t = xv.x, xs = xv.y;
        float s1, c1;
        __sincosf(1.5707963267948966f * xs, &s1, &c1);
        float cc[5], ss[5];
        cc[0] = c1; ss[0] = s1;
        #pragma unroll
        for (int m = 1; m < 5; ++m) {
            cc[m] = cc[m - 1] * c1 - ss[m - 1] * s1;
            ss[m] = ss[m - 1] * c1 + cc[m - 1] * s1;
        }
        float e0[8] = {t, 1.f, cc[0], cc[1], cc[2], cc[3], cc[4], ss[0]};
        float e1[8] = {ss[1], ss[2], ss[3], ss[4], 0.f, 0.f, 0.f, 0.f};
        half8 a;
        #pragma unroll
        for (int v = 0; v < 8; ++v) {
            float x = (g == 0) ? e0[v] : (g == 1) ? e1[v] : 0.f;
            a[v] = (_Float16)x;
        }
        axe[st] = a;
    }

    // ---- UVH stage: U,D=V-U packed f16 pairs in regs; H -> LDS tiles ----
    unsigned int Upk[2][4][2], Dpk[2][4][2];
    #pragma unroll
    for (int ns = 0; ns < 4; ++ns) {
        half8 wU = wsv[(0 * 4 + ns) * 64 + l];
        half8 wV = wsv[(1 * 4 + ns) * 64 + l];
        half8 wH = wsv[(2 * 4 + ns) * 64 + l];
        #pragma unroll
        for (int st = 0; st < 2; ++st) {
            f32x4 z4 = {0.f, 0.f, 0.f, 0.f};
            f32x4 aU = __builtin_amdgcn_mfma_f32_16x16x32_f16(wU, axe[st], z4, 0, 0, 0);
            f32x4 aV = __builtin_amdgcn_mfma_f32_16x16x32_f16(wV, axe[st], z4, 0, 0, 0);
            f32x4 aH = __builtin_amdgcn_mfma_f32_16x16x32_f16(wH, axe[st], z4, 0, 0, 0);
            unsigned int* tb = &tile[wave][st][0];
            if (ns < 3) {
                float u0 = fast_tanh(aU[0]), u1 = fast_tanh(aU[1]);
                float u2 = fast_tanh(aU[2]), u3 = fast_tanh(aU[3]);
                float v0 = fast_tanh(aV[0]), v1 = fast_tanh(aV[1]);
                float v2 = fast_tanh(aV[2]), v3 = fast_tanh(aV[3]);
                Upk[st][ns][0] = pk2(u0, u1);      Upk[st][ns][1] = pk2(u2, u3);
                Dpk[st][ns][0] = pk2(v0 - u0, v1 - u1);
                Dpk[st][ns][1] = pk2(v2 - u2, v3 - u3);
                uint2v hw;
                hw[0] = pk2(fast_tanh(aH[0]), fast_tanh(aH[1]));
                hw[1] = pk2(fast_tanh(aH[2]), fast_tanh(aH[3]));
                *(uint2v*)(tb + ow[ns]) = hw;
            } else {          // features 48,49 real; 50 = bias lane (1.0); 51+ dead
                float u0 = fast_tanh(aU[0]), u1 = fast_tanh(aU[1]);
                float v0 = fast_tanh(aV[0]), v1 = fast_tanh(aV[1]);
                Upk[st][3][0] = pk2(u0, u1);            Upk[st][3][1] = 0u;
                Dpk[st][3][0] = pk2(v0 - u0, v1 - u1);  Dpk[st][3][1] = 0u;
                uint2v hw;
                hw[0] = pk2(fast_tanh(aH[0]), fast_tanh(aH[1]));
                hw[1] = 0x00003C00u;                    // (1.0h, 0.0h)
                *(uint2v*)(tb + ow[3]) = hw;
            }
        }
    }

    // ---- Z layers 0..2: read B-frags, MFMA, f32 gate, pack, write back ----
    #pragma unroll 1
    for (int li = 0; li < 3; ++li) {
        half8 wz[4][2];
        #pragma unroll
        for (int ns = 0; ns < 4; ++ns)
            #pragma unroll
            for (int ks = 0; ks < 2; ++ks)
                wz[ns][ks] = wsv[768 + ((li * 4 + ns) * 2 + ks) * 64 + l];
        #pragma unroll
        for (int st = 0; st < 2; ++st) {
            unsigned int* tb = &tile[wave][st][0];
            uint4v q0 = *(const uint4v*)(tb + orx[0]);
            uint4v q1 = *(const uint4v*)(tb + orx[1]);
            half8 b0 = __builtin_bit_cast(half8, q0);
            half8 b1 = __builtin_bit_cast(half8, q1);
            #pragma unroll
            for (int ns = 0; ns < 4; ++ns) {
                f32x4 z4 = {0.f, 0.f, 0.f, 0.f};
                f32x4 acc = __builtin_amdgcn_mfma_f32_16x16x32_f16(wz[ns][0], b0, z4, 0, 0, 0);
                acc = __builtin_amdgcn_mfma_f32_16x16x32_f16(wz[ns][1], b1, acc, 0, 0, 0);
                half2v u01 = upk(Upk[st][ns][0]), d01 = upk(Dpk[st][ns][0]);
                float z0 = fast_tanh(acc[0]), z1 = fast_tanh(acc[1]);
                uint2v gw;
                gw[0] = pk2(fmaf(z0, (float)d01[0], (float)u01[0]),
                            fmaf(z1, (float)d01[1], (float)u01[1]));
                if (ns < 3) {
                    half2v u23 = upk(Upk[st][ns][1]), d23 = upk(Dpk[st][ns][1]);
                    float z2 = fast_tanh(acc[2]), z3 = fast_tanh(acc[3]);
                    gw[1] = pk2(fmaf(z2, (float)d23[0], (float)u23[0]),
                                fmaf(z3, (float)d23[1], (float)u23[1]));
                } else {
                    gw[1] = 0x00003C00u;                // keep bias lane = 1.0
                }
                *(uint2v*)(tb + ow[ns]) = gw;
            }
        }
    }

    // ---- last Z layer fused with F projection (no LDS write-back) ----
    {
        half8 wz[4][2];
        #pragma unroll
        for (int ns = 0; ns < 4; ++ns)
            #pragma unroll
            for (int ks = 0; ks < 2; ++ks)
                wz[ns][ks] = wsv[768 + ((3 * 4 + ns) * 2 + ks) * 64 + l];
        float fb = F_b[0];
        #pragma unroll
        for (int st = 0; st < 2; ++st) {
            unsigned int* tb = &tile[wave][st][0];
            uint4v q0 = *(const uint4v*)(tb + orx[0]);
            uint4v q1 = *(const uint4v*)(tb + orx[1]);
            half8 b0 = __builtin_bit_cast(half8, q0);
            half8 b1 = __builtin_bit_cast(half8, q1);
            float s = 0.f;
            #pragma unroll
            for (int ns = 0; ns < 4; ++ns) {
                f32x4 z4 = {0.f, 0.f, 0.f, 0.f};
                f32x4 acc = __builtin_amdgcn_mfma_f32_16x16x32_f16(wz[ns][0], b0, z4, 0, 0, 0);
                acc = __builtin_amdgcn_mfma_f32_16x16x32_f16(wz[ns][1], b1, acc, 0, 0, 0);
                f32x4 fw = *(const f32x4*)(Fp + 16 * ns + 4 * g);
                #pragma unroll
                for (int r = 0; r < 4; ++r) {
                    float z = fast_tanh(acc[r]);
                    half2v u2 = upk(Upk[st][ns][r >> 1]);
                    half2v d2 = upk(Dpk[st][ns][r >> 1]);
                    float gg = fmaf(z, (float)d2[r & 1], (float)u2[r & 1]);
                    s = fmaf(gg, fw[r], s);
                }
            }
            s += __shfl_xor(s, 16);
            s += __shfl_xor(s, 32);
            if (l < 16) out[pbase + st * 16 + cl] = s + fb;
        }
    }
}

extern "C" void kernel_launch(void* const* d_in, const int* in_sizes, int n_in,
                              void* d_out, int out_size, void* d_ws, size_t ws_size,
                              hipStream_t stream) {
    const float* X   = (const float*)d_in[0];
    const float* U_W = (const float*)d_in[1];
    const float* U_b = (const float*)d_in[2];
    const float* V_W = (const float*)d_in[3];
    const float* V_b = (const float*)d_in[4];
    const float* H_W = (const float*)d_in[5];
    const float* H_b = (const float*)d_in[6];
    const float* Z_W = (const float*)d_in[7];
    const float* Z_b = (const float*)d_in[8];
    const float* F_W = (const float*)d_in[9];
    const float* F_b = (const float*)d_in[10];
    float* out = (float*)d_out;
    _Float16* ws16 = (_Float16*)d_ws;

    int N = in_sizes[0] / 2;          // 1048576; 128 points per block
    prep_weights<<<45, 64, 0, stream>>>(U_W, U_b, V_W, V_b, H_W, H_b, Z_W, Z_b, F_W, ws16);
    int blocks = N / 128;
    mlp_mfma<<<blocks, 256, 0, stream>>>(X, ws16, F_b, out);
}

// Round 5
// 95.904 us; speedup vs baseline: 4.9030x; 1.2786x over previous
//
#include <hip/hip_runtime.h>

typedef _Float16 half8 __attribute__((ext_vector_type(8)));
typedef _Float16 half2v __attribute__((ext_vector_type(2)));
typedef float f32x4 __attribute__((ext_vector_type(4)));
typedef unsigned int uint2v __attribute__((ext_vector_type(2)));
typedef unsigned int uint4v __attribute__((ext_vector_type(4)));

#define HID 50
#define KSC 2.8853900817779268f   // 2*log2(e), folded into all W/b at prep

// r = 1/(1 + 2^a)  where a = 2*log2(e)*s  =>  tanh(s) = 1 - 2r
__device__ __forceinline__ float sigr(float a) {
    return __builtin_amdgcn_rcpf(1.0f + __builtin_amdgcn_exp2f(a));
}
__device__ __forceinline__ half2v pk2h(float a, float b) {
    return __builtin_bit_cast(half2v, __builtin_amdgcn_cvt_pkrtz(a, b));
}
__device__ __forceinline__ unsigned int h2u(half2v h) {
    return __builtin_bit_cast(unsigned int, h);
}

// ---------- weight prep: 45 blocks x 64 threads ----------
// half8-block b, lane l (g=l>>4, cl=l&15), elem v -> W[k = 8g+v (+32ks)][col = cl+16nt]
//   b in [0,12):  UVH  b = m*4 + nt           (K=32 padded from 12, bias folded at k==1)
//   b in [12,44): Z    b = 12 + (li*4+nt)*2 + ks  (K=64 padded from 50, bias row at k==50)
//   block 44: F_W padded to 64 floats at f16-offset 22528
// All UVH/Z weights and biases pre-scaled by KSC (they only feed tanh).
__global__ void prep_weights(const float* __restrict__ U_W, const float* __restrict__ U_b,
                             const float* __restrict__ V_W, const float* __restrict__ V_b,
                             const float* __restrict__ H_W, const float* __restrict__ H_b,
                             const float* __restrict__ Z_W, const float* __restrict__ Z_b,
                             const float* __restrict__ F_W,
                             _Float16* __restrict__ ws) {
    int b = blockIdx.x;
    int l = threadIdx.x;
    if (b == 44) {
        float* Fp = (float*)(ws + 22528);
        Fp[l] = (l < HID) ? F_W[l] : 0.f;
        return;
    }
    int g = l >> 4, cl = l & 15;
    half8 h;
    if (b < 12) {
        int m = b >> 2, nt = b & 3;
        const float* W = (m == 0) ? U_W : (m == 1) ? V_W : H_W;
        const float* B = (m == 0) ? U_b : (m == 1) ? V_b : H_b;
        int c = cl + 16 * nt;
        #pragma unroll
        for (int v = 0; v < 8; ++v) {
            int k = 8 * g + v;
            float x = 0.f;
            if (k < 12 && c < HID) { x = W[k * HID + c]; if (k == 1) x += B[c]; }
            h[v] = (_Float16)(x * KSC);
        }
    } else {
        int zb = b - 12;
        int li = zb >> 3, nt = (zb >> 1) & 3, ks = zb & 1;
        int c = cl + 16 * nt;
        #pragma unroll
        for (int v = 0; v < 8; ++v) {
            int k = ks * 32 + 8 * g + v;
            float x = 0.f;
            if (c < HID) {
                if (k < HID)       x = Z_W[li * (HID * HID) + k * HID + c];
                else if (k == HID) x = Z_b[li * HID + c];   // bias row (input feature 50 == 1.0)
            }
            h[v] = (_Float16)(x * KSC);
        }
    }
    *(half8*)(ws + (size_t)b * 512 + (size_t)l * 8) = h;
}

// ---------- main: 1 block = 4 waves, 1 wave = 32 points (2 subtiles of 16) ----------
// Transposed GEMMs: D = Wfrag(A) x Xfrag(B); D[feature=4g+r (+16ns)][point=cl].
// Inter-layer tile: per (wave,st) 16 cols (points) x 32 words (feature pairs),
// word p at column cl stored at word idx  cl*32 + (p ^ ((cl&7)<<2)).
__global__ __launch_bounds__(256, 3) void mlp_mfma(
        const float* __restrict__ X, const _Float16* __restrict__ ws,
        const float* __restrict__ F_b, float* __restrict__ out) {
    __shared__ __align__(16) unsigned int tile[4][2][512];   // 16 KB
    const int tid = threadIdx.x;
    const int wave = tid >> 6, l = tid & 63;
    const int g = l >> 4, cl = l & 15;
    const int pbase = blockIdx.x * 128 + wave * 32;
    const half8* __restrict__ wsv = (const half8*)ws;
    const float* __restrict__ Fp = (const float*)(ws + 22528);

    const int S = (cl & 7) << 2;
    int ow[4], orx[2];
    #pragma unroll
    for (int ns = 0; ns < 4; ++ns) ow[ns] = ((8 * ns + 2 * g) ^ S) + cl * 32;
    orx[0] = ((4 * g) ^ S) + cl * 32;
    orx[1] = ((16 + 4 * g) ^ S) + cl * 32;

    // ---- Fourier embedding B-frags: lane holds Xe[point=cl][k=8g+v] ----
    half8 axe[2];
    #pragma unroll
    for (int st = 0; st < 2; ++st) {
        int p = pbase + st * 16 + cl;
        float2 xv = *(const float2*)(X + 2 * p);
        float t = xv.x, xs = xv.y;
        // sin/cos(pi/2 * xs) via HW units: input in revolutions = xs/4
        float rv = xs * 0.25f;
        rv = rv - floorf(rv);
        float s1 = __builtin_amdgcn_sinf(rv);
        float c1 = __builtin_amdgcn_cosf(rv);
        float cc[5], ss[5];
        cc[0] = c1; ss[0] = s1;
        #pragma unroll
        for (int m = 1; m < 5; ++m) {
            cc[m] = cc[m - 1] * c1 - ss[m - 1] * s1;
            ss[m] = ss[m - 1] * c1 + cc[m - 1] * s1;
        }
        float e0[8] = {t, 1.f, cc[0], cc[1], cc[2], cc[3], cc[4], ss[0]};
        float e1[8] = {ss[1], ss[2], ss[3], ss[4], 0.f, 0.f, 0.f, 0.f};
        half8 a;
        #pragma unroll
        for (int v = 0; v < 8; ++v) {
            float x = (g == 0) ? e0[v] : (g == 1) ? e1[v] : 0.f;
            a[v] = (_Float16)x;
        }
        axe[st] = a;
    }

    // ---- UVH stage: keep packed V and M = -2*(V-U); H -> LDS tiles ----
    // gate identity: U + tanh(s)*(V-U) = V + r*M  with r = sigr(acc)
    half2v Vh[2][4][2], Mh[2][4][2];
    #pragma unroll
    for (int ns = 0; ns < 4; ++ns) {
        half8 wU = wsv[(0 * 4 + ns) * 64 + l];
        half8 wV = wsv[(1 * 4 + ns) * 64 + l];
        half8 wH = wsv[(2 * 4 + ns) * 64 + l];
        #pragma unroll
        for (int st = 0; st < 2; ++st) {
            f32x4 z4 = {0.f, 0.f, 0.f, 0.f};
            f32x4 aU = __builtin_amdgcn_mfma_f32_16x16x32_f16(wU, axe[st], z4, 0, 0, 0);
            f32x4 aV = __builtin_amdgcn_mfma_f32_16x16x32_f16(wV, axe[st], z4, 0, 0, 0);
            f32x4 aH = __builtin_amdgcn_mfma_f32_16x16x32_f16(wH, axe[st], z4, 0, 0, 0);
            unsigned int* tb = &tile[wave][st][0];
            if (ns < 3) {
                float rU0 = sigr(aU[0]), rU1 = sigr(aU[1]), rU2 = sigr(aU[2]), rU3 = sigr(aU[3]);
                float rV0 = sigr(aV[0]), rV1 = sigr(aV[1]), rV2 = sigr(aV[2]), rV3 = sigr(aV[3]);
                float rH0 = sigr(aH[0]), rH1 = sigr(aH[1]), rH2 = sigr(aH[2]), rH3 = sigr(aH[3]);
                // V = 1-2rV ; M = -2(V-U) = 4(rV-rU) ; H = 1-2rH   (f32, then pack)
                float v0 = fmaf(-2.f, rV0, 1.f), v1 = fmaf(-2.f, rV1, 1.f);
                float v2 = fmaf(-2.f, rV2, 1.f), v3 = fmaf(-2.f, rV3, 1.f);
                float m0 = (rV0 - rU0) * 4.f, m1 = (rV1 - rU1) * 4.f;
                float m2 = (rV2 - rU2) * 4.f, m3 = (rV3 - rU3) * 4.f;
                float h0 = fmaf(-2.f, rH0, 1.f), h1 = fmaf(-2.f, rH1, 1.f);
                float h2 = fmaf(-2.f, rH2, 1.f), h3 = fmaf(-2.f, rH3, 1.f);
                Vh[st][ns][0] = pk2h(v0, v1);  Vh[st][ns][1] = pk2h(v2, v3);
                Mh[st][ns][0] = pk2h(m0, m1);  Mh[st][ns][1] = pk2h(m2, m3);
                uint2v hw;
                hw[0] = h2u(pk2h(h0, h1));
                hw[1] = h2u(pk2h(h2, h3));
                *(uint2v*)(tb + ow[ns]) = hw;
            } else {          // features 48,49 real; 50 = bias lane (1.0); 51+ dead
                float rU0 = sigr(aU[0]), rU1 = sigr(aU[1]);
                float rV0 = sigr(aV[0]), rV1 = sigr(aV[1]);
                float rH0 = sigr(aH[0]), rH1 = sigr(aH[1]);
                float v0 = fmaf(-2.f, rV0, 1.f), v1 = fmaf(-2.f, rV1, 1.f);
                float m0 = (rV0 - rU0) * 4.f, m1 = (rV1 - rU1) * 4.f;
                float h0 = fmaf(-2.f, rH0, 1.f), h1 = fmaf(-2.f, rH1, 1.f);
                Vh[st][3][0] = pk2h(v0, v1);  Vh[st][3][1] = pk2h(0.f, 0.f);
                Mh[st][3][0] = pk2h(m0, m1);  Mh[st][3][1] = pk2h(0.f, 0.f);
                uint2v hw;
                hw[0] = h2u(pk2h(h0, h1));
                hw[1] = 0x00003C00u;                    // (1.0h, 0.0h)
                *(uint2v*)(tb + ow[3]) = hw;
            }
        }
    }

    // ---- Z layers 0..2: MFMA -> r -> one pk_fma gate -> write back ----
    #pragma unroll
    for (int li = 0; li < 3; ++li) {
        half8 wz[4][2];
        #pragma unroll
        for (int ns = 0; ns < 4; ++ns)
            #pragma unroll
            for (int ks = 0; ks < 2; ++ks)
                wz[ns][ks] = wsv[768 + ((li * 4 + ns) * 2 + ks) * 64 + l];
        #pragma unroll
        for (int st = 0; st < 2; ++st) {
            unsigned int* tb = &tile[wave][st][0];
            uint4v q0 = *(const uint4v*)(tb + orx[0]);
            uint4v q1 = *(const uint4v*)(tb + orx[1]);
            half8 b0 = __builtin_bit_cast(half8, q0);
            half8 b1 = __builtin_bit_cast(half8, q1);
            #pragma unroll
            for (int ns = 0; ns < 4; ++ns) {
                f32x4 z4 = {0.f, 0.f, 0.f, 0.f};
                f32x4 acc = __builtin_amdgcn_mfma_f32_16x16x32_f16(wz[ns][0], b0, z4, 0, 0, 0);
                acc = __builtin_amdgcn_mfma_f32_16x16x32_f16(wz[ns][1], b1, acc, 0, 0, 0);
                half2v r01 = pk2h(sigr(acc[0]), sigr(acc[1]));
                half2v g01 = r01 * Mh[st][ns][0] + Vh[st][ns][0];   // v_pk_fma_f16
                uint2v gw;
                gw[0] = h2u(g01);
                if (ns < 3) {
                    half2v r23 = pk2h(sigr(acc[2]), sigr(acc[3]));
                    half2v g23 = r23 * Mh[st][ns][1] + Vh[st][ns][1];
                    gw[1] = h2u(g23);
                } else {
                    gw[1] = 0x00003C00u;                // keep bias lane = 1.0
                }
                *(uint2v*)(tb + ow[ns]) = gw;
            }
        }
    }

    // ---- last Z layer fused with F projection (f32 gate, no LDS write-back) ----
    {
        half8 wz[4][2];
        #pragma unroll
        for (int ns = 0; ns < 4; ++ns)
            #pragma unroll
            for (int ks = 0; ks < 2; ++ks)
                wz[ns][ks] = wsv[768 + ((3 * 4 + ns) * 2 + ks) * 64 + l];
        float fb = F_b[0];
        #pragma unroll
        for (int st = 0; st < 2; ++st) {
            unsigned int* tb = &tile[wave][st][0];
            uint4v q0 = *(const uint4v*)(tb + orx[0]);
            uint4v q1 = *(const uint4v*)(tb + orx[1]);
            half8 b0 = __builtin_bit_cast(half8, q0);
            half8 b1 = __builtin_bit_cast(half8, q1);
            float s = 0.f;
            #pragma unroll
            for (int ns = 0; ns < 4; ++ns) {
                f32x4 z4 = {0.f, 0.f, 0.f, 0.f};
                f32x4 acc = __builtin_amdgcn_mfma_f32_16x16x32_f16(wz[ns][0], b0, z4, 0, 0, 0);
                acc = __builtin_amdgcn_mfma_f32_16x16x32_f16(wz[ns][1], b1, acc, 0, 0, 0);
                f32x4 fw = *(const f32x4*)(Fp + 16 * ns + 4 * g);
                const int RMAX = (ns < 3) ? 4 : 2;   // padded features have fw == 0
                #pragma unroll
                for (int r = 0; r < RMAX; ++r) {
                    float rr = sigr(acc[r]);
                    half2v m2 = Mh[st][ns][r >> 1];
                    half2v vv = Vh[st][ns][r >> 1];
                    float gg = fmaf(rr, (float)m2[r & 1], (float)vv[r & 1]);
                    s = fmaf(gg, fw[r], s);
                }
            }
            s += __shfl_xor(s, 16);
            s += __shfl_xor(s, 32);
            if (l < 16) out[pbase + st * 16 + cl] = s + fb;
        }
    }
}

extern "C" void kernel_launch(void* const* d_in, const int* in_sizes, int n_in,
                              void* d_out, int out_size, void* d_ws, size_t ws_size,
                              hipStream_t stream) {
    const float* X   = (const float*)d_in[0];
    const float* U_W = (const float*)d_in[1];
    const float* U_b = (const float*)d_in[2];
    const float* V_W = (const float*)d_in[3];
    const float* V_b = (const float*)d_in[4];
    const float* H_W = (const float*)d_in[5];
    const float* H_b = (const float*)d_in[6];
    const float* Z_W = (const float*)d_in[7];
    const float* Z_b = (const float*)d_in[8];
    const float* F_W = (const float*)d_in[9];
    const float* F_b = (const float*)d_in[10];
    float* out = (float*)d_out;
    _Float16* ws16 = (_Float16*)d_ws;

    int N = in_sizes[0] / 2;          // 1048576; 128 points per block
    prep_weights<<<45, 64, 0, stream>>>(U_W, U_b, V_W, V_b, H_W, H_b, Z_W, Z_b, F_W, ws16);
    int blocks = N / 128;
    mlp_mfma<<<blocks, 256, 0, stream>>>(X, ws16, F_b, out);
}